// Round 2
// baseline (158.412 us; speedup 1.0000x reference)
//
#include <hip/hip_runtime.h>
#include <math.h>

#define WID 512
#define HEI 512
#define NB  16
#define HW  ((size_t)HEI * WID)
#define NEG_INF (-INFINITY)

// -------------------------------------------------------------------------
// Kernel A: fused channel-min (3 ch) + horizontal 35-max (-inf pad).
// One full image row per block (256 thr, 2 outputs/thr): halo loaded once.
// Window decomposition: max over [a,a+34] = max(3 left elems, 8 groups-of-4,
// 3 right elems) — exactly 8 fully-covered groups for every alignment.
// Output ws layout: [z=tensor*16+b][h][w] fp32.
// -------------------------------------------------------------------------
__global__ __launch_bounds__(256) void hmax_kernel(
    const float* __restrict__ rin, const float* __restrict__ tin,
    float* __restrict__ ws)
{
    const int h = blockIdx.x;       // 0..511
    const int z = blockIdx.y;       // 0..31
    const int b = z & 15;
    const float* __restrict__ in = (z < NB) ? rin : tin;
    const float* __restrict__ p  = in + (size_t)b * 3 * HW + (size_t)h * WID;

    __shared__ float sm[548];   // 546 used: 512 outputs + 2*17 halo
    __shared__ float gm[137];   // groups of 4

    const int tid = threadIdx.x;

    // Channel-min into LDS (coalesced; inputs read once -> nontemporal)
    for (int i = tid; i < 548; i += 256) {
        int w = i - 17;
        float v = NEG_INF;
        if (w >= 0 && w < WID) {
            float a0 = __builtin_nontemporal_load(p + w);
            float a1 = __builtin_nontemporal_load(p + HW + w);
            float a2 = __builtin_nontemporal_load(p + 2 * HW + w);
            v = fminf(fminf(a0, a1), a2);
        }
        sm[i] = v;
    }
    __syncthreads();

    for (int g = tid; g < 137; g += 256) {
        gm[g] = fmaxf(fmaxf(sm[4*g], sm[4*g+1]), fmaxf(sm[4*g+2], sm[4*g+3]));
    }
    __syncthreads();

    float* __restrict__ wp = ws + (size_t)z * HW + (size_t)h * WID;
    #pragma unroll
    for (int rep = 0; rep < 2; ++rep) {
        const int a  = tid + rep * 256;   // output w; window = sm[a .. a+34]
        const int bb = a + 34;
        const int j0 = (a + 3) >> 2;      // exactly 8 covered groups, no clamp
        float m = fmaxf(fmaxf(sm[a], sm[a+1]), sm[a+2]);
        m = fmaxf(m, fmaxf(fmaxf(sm[bb], sm[bb-1]), sm[bb-2]));
        #pragma unroll
        for (int j = 0; j < 8; ++j) m = fmaxf(m, gm[j0 + j]);
        wp[a] = m;
    }
}

// -------------------------------------------------------------------------
// Kernel B: vertical 35-max (both tensors) + |r-t| + block reduce + atomic.
// grid (8,8,16) = 1024 blocks = 4 blocks/CU exactly (LDS 33 KB allows 4).
// r-tile kept in 16 registers/thread (same thread writes & reads it).
// -------------------------------------------------------------------------
__global__ __launch_bounds__(256) void vmax_kernel(
    const float* __restrict__ rh, const float* __restrict__ th,
    float* __restrict__ acc)
{
    __shared__ float sm[100][64];  // 98 region rows + 2 -inf pad rows
    __shared__ float gm[25][64];   // groups-of-4 row maxima
    __shared__ float red[256];

    const int tid = threadIdx.x;
    const int col = tid & 63;
    const int ty  = tid >> 6;       // 0..3
    const int w0  = blockIdx.x * 64;
    const int h0  = blockIdx.y * 64;
    const int b   = blockIdx.z;

    float rtv[16];                  // r-tensor results (registers, static idx)
    float tsum = 0.0f;

    #pragma unroll
    for (int tensor = 0; tensor < 2; ++tensor) {
        const float* __restrict__ pb =
            ((tensor == 0) ? rh : th) + (size_t)b * HW;

        // Stage region rows [h0-17, h0+80] (98 rows) + 2 pad rows
        for (int i = tid; i < 100 * 64; i += 256) {
            int row = i >> 6;
            int c   = i & 63;
            int hh  = h0 - 17 + row;
            float v = NEG_INF;
            if (row < 98 && hh >= 0 && hh < HEI)
                v = pb[(size_t)hh * WID + w0 + c];
            sm[row][c] = v;
        }
        __syncthreads();

        for (int i = tid; i < 25 * 64; i += 256) {
            int g = i >> 6;
            int c = i & 63;
            gm[g][c] = fmaxf(fmaxf(sm[4*g][c], sm[4*g+1][c]),
                             fmaxf(sm[4*g+2][c], sm[4*g+3][c]));
        }
        __syncthreads();

        #pragma unroll
        for (int k = 0; k < 16; ++k) {
            const int a  = ty * 16 + k;     // window region rows [a, a+34]
            const int bb = a + 34;
            const int j0 = (a + 3) >> 2;    // exactly 8 covered groups
            float m = fmaxf(fmaxf(sm[a][col], sm[a+1][col]), sm[a+2][col]);
            m = fmaxf(m, fmaxf(fmaxf(sm[bb][col], sm[bb-1][col]), sm[bb-2][col]));
            #pragma unroll
            for (int j = 0; j < 8; ++j) m = fmaxf(m, gm[j0 + j][col]);
            if (tensor == 0) rtv[k] = m;
            else             tsum += fabsf(rtv[k] - m);
        }
        __syncthreads();   // before sm/gm reuse next tensor
    }

    // Block reduction -> one atomic per block
    red[tid] = tsum;
    __syncthreads();
    for (int s = 128; s > 0; s >>= 1) {
        if (tid < s) red[tid] += red[tid + s];
        __syncthreads();
    }
    if (tid == 0) atomicAdd(acc, red[0]);
}

// -------------------------------------------------------------------------
// Kernel C: finalize — sigmoid(mean)
// -------------------------------------------------------------------------
__global__ void finalize_kernel(const float* __restrict__ acc,
                                float* __restrict__ out)
{
    float s = acc[0] / 4194304.0f;   // 16*512*512
    out[0] = 1.0f / (1.0f + expf(-s));
}

// -------------------------------------------------------------------------
extern "C" void kernel_launch(void* const* d_in, const int* in_sizes, int n_in,
                              void* d_out, int out_size, void* d_ws, size_t ws_size,
                              hipStream_t stream) {
    const float* rin = (const float*)d_in[0];   // restored [16,3,512,512]
    const float* tin = (const float*)d_in[1];   // target   [16,3,512,512]
    float* out = (float*)d_out;

    float* wsf = (float*)d_ws;
    float* rh  = wsf;                         // [16][512][512]
    float* th  = wsf + (size_t)NB * HW;       // [16][512][512]
    float* acc = wsf + (size_t)2 * NB * HW;   // 1 float accumulator

    hipMemsetAsync(acc, 0, sizeof(float), stream);

    dim3 gA(HEI, 2 * NB);
    hipLaunchKernelGGL(hmax_kernel, gA, dim3(256), 0, stream, rin, tin, wsf);

    dim3 gB(WID / 64, HEI / 64, NB);
    hipLaunchKernelGGL(vmax_kernel, gB, dim3(256), 0, stream, rh, th, acc);

    hipLaunchKernelGGL(finalize_kernel, dim3(1), dim3(1), 0, stream, acc, out);
}

// Round 3
// 154.022 us; speedup vs baseline: 1.0285x; 1.0285x over previous
//
#include <hip/hip_runtime.h>
#include <math.h>

#define WID 512
#define HEI 512
#define NB  16
#define HW  ((size_t)HEI * WID)
#define NEG_INF (-INFINITY)

typedef float f4 __attribute__((ext_vector_type(4)));

// -------------------------------------------------------------------------
// Kernel A: fused channel-min (3ch) + horizontal 35-max (-inf pad).
// 2 rows/block, 256 thr. Each thread: 3x float4 global loads (one/channel),
// register min -> LDS; 4 outputs via 11 conflict-free ds_read_b128 + quad-max
// tree. Halo is constant -inf (never loaded from global).
// sm[row][20+x] = channel-min at col x; window for out w = idx [w+3, w+37].
// Exactly 8 fully-covered quads per window alignment (proof: a=4q+r cases).
// -------------------------------------------------------------------------
__global__ __launch_bounds__(256) void hmax_kernel(
    const float* __restrict__ rin, const float* __restrict__ tin,
    float* __restrict__ ws, float* __restrict__ acc)
{
    __shared__ float sm[2][552];          // 552*4 = 2208 B/row, 16B-aligned
    const int tid = threadIdx.x;
    const int row = tid >> 7;             // 0..1
    const int t   = tid & 127;            // float4 index within row
    const int h   = blockIdx.x * 2 + row;
    const int z   = blockIdx.y;           // tensor*16 + b
    const int b   = z & 15;
    const float* __restrict__ in = (z < NB) ? rin : tin;

    // zero [sum, ticket] once; visible to vmax at kernel boundary
    if (blockIdx.x == 0 && blockIdx.y == 0 && tid < 2) acc[tid] = 0.0f;

    // constant -inf halo: idx 0..19 and 532..551
    if (tid < 80) {
        int r2 = tid / 40, j = tid % 40;
        sm[r2][(j < 20) ? j : (j + 512)] = NEG_INF;
    }

    const float* __restrict__ p = in + (size_t)b * 3 * HW + (size_t)h * WID;
    f4 a0 = __builtin_nontemporal_load((const f4*)p + t);
    f4 a1 = __builtin_nontemporal_load((const f4*)(p + HW) + t);
    f4 a2 = __builtin_nontemporal_load((const f4*)(p + 2 * HW) + t);
    f4 v;
    v.x = fminf(fminf(a0.x, a1.x), a2.x);
    v.y = fminf(fminf(a0.y, a1.y), a2.y);
    v.z = fminf(fminf(a0.z, a1.z), a2.z);
    v.w = fminf(fminf(a0.w, a1.w), a2.w);
    *(f4*)&sm[row][20 + 4 * t] = v;
    __syncthreads();

    // outputs w = 4t..4t+3; need idx [4t+3, 4t+40] c sm4[t..t+10]
    const f4* __restrict__ smr = (const f4*)sm[row];
    f4 vv[11];
    #pragma unroll
    for (int i = 0; i < 11; ++i) vv[i] = smr[t + i];
    float q[10];
    #pragma unroll
    for (int i = 1; i <= 9; ++i)
        q[i] = fmaxf(fmaxf(vv[i].x, vv[i].y), fmaxf(vv[i].z, vv[i].w));
    float Q28 = fmaxf(fmaxf(fmaxf(q[2], q[3]), fmaxf(q[4], q[5])),
                      fmaxf(fmaxf(q[6], q[7]), q[8]));
    float Q18 = fmaxf(Q28, q[1]);   // quads 1..8
    float Q29 = fmaxf(Q28, q[9]);   // quads 2..9
    float s01 = fmaxf(vv[9].x, vv[9].y);
    float s23 = fmaxf(vv[1].z, vv[1].w);
    f4 o;
    o.x = fmaxf(fmaxf(Q18, vv[0].w), s01);            // [4t+3, 4t+37]
    o.y = fmaxf(Q18, fmaxf(s01, vv[9].z));            // [4t+4, 4t+38]
    o.z = fmaxf(fmaxf(Q29, vv[1].y), s23);            // [4t+5, 4t+39]
    o.w = fmaxf(Q29, fmaxf(s23, vv[10].x));           // [4t+6, 4t+40]
    *((f4*)(ws + (size_t)z * HW + (size_t)h * WID) + t) = o;
}

// -------------------------------------------------------------------------
// Kernel B: vertical 35-max (both tensors) + |r-t| + reduce + fused finalize.
// grid (8,8,16) = 1024 blocks. Staging via float4; per-thread 50-row column
// in registers (conflict-free b32 column reads), quad-max decomposition.
// Last block (atomic ticket) computes sigmoid(mean) -> out.
// -------------------------------------------------------------------------
__global__ __launch_bounds__(256) void vmax_kernel(
    const float* __restrict__ ws, float* __restrict__ acc,
    float* __restrict__ out)
{
    __shared__ float sm[98][64];   // region rows [h0-17, h0+80]
    __shared__ float red[4];
    const int tid = threadIdx.x;
    const int col = tid & 63;
    const int ty  = tid >> 6;      // 0..3 -> output rows ty*16..ty*16+15
    const int w0  = blockIdx.x * 64;
    const int h0  = blockIdx.y * 64;
    const int b   = blockIdx.z;

    float rtv[16];
    float tsum = 0.0f;

    #pragma unroll
    for (int tensor = 0; tensor < 2; ++tensor) {
        const float* __restrict__ pb = ws + (size_t)(tensor * NB + b) * HW;
        #pragma unroll
        for (int i0 = 0; i0 < 1568; i0 += 256) {    // 98 rows * 16 float4
            int i = i0 + tid;
            if (i < 1568) {
                int r = i >> 4, c4 = i & 15;
                int hh = h0 - 17 + r;
                f4 v = {NEG_INF, NEG_INF, NEG_INF, NEG_INF};
                if (hh >= 0 && hh < HEI)
                    v = ((const f4*)pb)[hh * 128 + (w0 >> 2) + c4];
                *(f4*)&sm[r][c4 * 4] = v;
            }
        }
        __syncthreads();

        float vc[50];
        #pragma unroll
        for (int i = 0; i < 50; ++i) vc[i] = sm[ty * 16 + i][col];
        float q[12];
        #pragma unroll
        for (int i = 0; i < 12; ++i)
            q[i] = fmaxf(fmaxf(vc[4*i], vc[4*i+1]), fmaxf(vc[4*i+2], vc[4*i+3]));
        #pragma unroll
        for (int m = 0; m < 4; ++m) {
            // outputs k = 4m+j; window local rows [k, k+34]
            float Qc = fmaxf(fmaxf(fmaxf(q[m+1], q[m+2]), fmaxf(q[m+3], q[m+4])),
                             fmaxf(fmaxf(q[m+5], q[m+6]), q[m+7]));
            float A  = fmaxf(Qc, q[m+8]);
            float o0 = fmaxf(fmaxf(Qc, q[m]),
                             fmaxf(fmaxf(vc[4*m+32], vc[4*m+33]), vc[4*m+34]));
            float o1 = fmaxf(A, fmaxf(fmaxf(vc[4*m+1], vc[4*m+2]), vc[4*m+3]));
            float o2 = fmaxf(A, fmaxf(fmaxf(vc[4*m+2], vc[4*m+3]), vc[4*m+36]));
            float o3 = fmaxf(A, fmaxf(fmaxf(vc[4*m+3], vc[4*m+36]), vc[4*m+37]));
            if (tensor == 0) {
                rtv[4*m] = o0; rtv[4*m+1] = o1; rtv[4*m+2] = o2; rtv[4*m+3] = o3;
            } else {
                tsum += fabsf(rtv[4*m]   - o0) + fabsf(rtv[4*m+1] - o1)
                      + fabsf(rtv[4*m+2] - o2) + fabsf(rtv[4*m+3] - o3);
            }
        }
        __syncthreads();
    }

    // wave shuffle reduce -> 4 partials -> block sum -> atomic + ticket
    #pragma unroll
    for (int off = 32; off > 0; off >>= 1)
        tsum += __shfl_down(tsum, off, 64);
    if ((tid & 63) == 0) red[ty] = tsum;
    __syncthreads();
    if (tid == 0) {
        float blocksum = red[0] + red[1] + red[2] + red[3];
        atomicAdd(acc, blocksum);
        __threadfence();
        unsigned tk = atomicAdd((unsigned*)(acc + 1), 1u);
        if (tk == 1023u) {                       // last of 1024 blocks
            float s = atomicAdd(acc, 0.0f);      // coherent read of final sum
            out[0] = 1.0f / (1.0f + expf(-s / 4194304.0f));
        }
    }
}

// -------------------------------------------------------------------------
extern "C" void kernel_launch(void* const* d_in, const int* in_sizes, int n_in,
                              void* d_out, int out_size, void* d_ws, size_t ws_size,
                              hipStream_t stream) {
    const float* rin = (const float*)d_in[0];   // restored [16,3,512,512]
    const float* tin = (const float*)d_in[1];   // target   [16,3,512,512]
    float* out = (float*)d_out;

    float* wsf = (float*)d_ws;                  // [2][16][512][512] + acc
    float* acc = wsf + (size_t)2 * NB * HW;     // [sum, ticket]

    dim3 gA(HEI / 2, 2 * NB);
    hipLaunchKernelGGL(hmax_kernel, gA, dim3(256), 0, stream, rin, tin, wsf, acc);

    dim3 gB(WID / 64, HEI / 64, NB);
    hipLaunchKernelGGL(vmax_kernel, gB, dim3(256), 0, stream, wsf, acc, out);
}